// Round 5
// baseline (254.245 us; speedup 1.0000x reference)
//
#include <hip/hip_runtime.h>

// Problem constants: T=512, B=64, D=1024, fp32.
#define T_DIM   512
#define BD      65536          // B*D floats per time slice
#define BD4     16384          // BD / 4 (float4 columns)
#define CHUNKS  8
#define CHUNK_T 64             // T_DIM / CHUNKS

// Native clang vector for nontemporal stores (HIP float4 is a class type,
// rejected by __builtin_nontemporal_store).
typedef float nfloat4 __attribute__((ext_vector_type(4)));

__device__ __forceinline__ float sigmoid_fast(float x) {
    // 1 / (1 + e^-x) via hw exp2 + hw rcp (~2 ULP, fine vs f32 reference)
    float e = __expf(-x);
    return __builtin_amdgcn_rcpf(1.0f + e);
}

// K1: per-column sum of each T-chunk (chunks 0..CHUNKS-2 only;
// the last chunk's sum is never needed as an offset).
__global__ __launch_bounds__(256)
void SumGoalHistory_chunksums(const float4* __restrict__ goal,
                              float4* __restrict__ sums) {
    int gid = blockIdx.x * 256 + threadIdx.x;     // [0, (CHUNKS-1)*BD4)
    int c = gid >> 14;                            // / BD4
    int i = gid & (BD4 - 1);
    const float4* p = goal + (size_t)c * CHUNK_T * BD4 + i;
    float sx = 0.f, sy = 0.f, sz = 0.f, sw = 0.f;
    #pragma unroll 8
    for (int t = 0; t < CHUNK_T; ++t) {
        float4 v = p[(size_t)t * BD4];
        sx += v.x; sy += v.y; sz += v.z; sw += v.w;
    }
    sums[c * BD4 + i] = make_float4(sx, sy, sz, sw);
}

// K2: each thread owns (chunk c, float4-column i). Offset = init + prefix of
// chunk sums, then 64-step sequential scan: acc += goal; out = sigmoid(acc).
__global__ __launch_bounds__(256)
void SumGoalHistory_scan(const float4* __restrict__ goal,
                         const float4* __restrict__ init,
                         const float4* __restrict__ sums,
                         float4* __restrict__ out) {
    int gid = blockIdx.x * 256 + threadIdx.x;     // [0, CHUNKS*BD4)
    int c = gid >> 14;
    int i = gid & (BD4 - 1);

    float4 a = init[i];
    float ax = a.x, ay = a.y, az = a.z, aw = a.w;
    // c is uniform per block (16384/256 = 64 blocks per chunk) -> no divergence
    for (int cc = 0; cc < c; ++cc) {
        float4 s = sums[cc * BD4 + i];
        ax += s.x; ay += s.y; az += s.z; aw += s.w;
    }

    const float4* p = goal + (size_t)c * CHUNK_T * BD4 + i;
    nfloat4*      o = (nfloat4*)out + (size_t)c * CHUNK_T * BD4 + i;
    #pragma unroll 4
    for (int t = 0; t < CHUNK_T; ++t) {
        float4 v = p[(size_t)t * BD4];
        ax += v.x; ay += v.y; az += v.z; aw += v.w;
        nfloat4 r;
        r.x = sigmoid_fast(ax);
        r.y = sigmoid_fast(ay);
        r.z = sigmoid_fast(az);
        r.w = sigmoid_fast(aw);
        __builtin_nontemporal_store(r, o + (size_t)t * BD4);
    }

    if (c == CHUNKS - 1) {
        // final_state written twice: d_out layout = outputs | final | final
        float4 f = make_float4(ax, ay, az, aw);
        float4* fin = out + (size_t)T_DIM * BD4;
        fin[i] = f;
        fin[BD4 + i] = f;
    }
}

extern "C" void kernel_launch(void* const* d_in, const int* in_sizes, int n_in,
                              void* d_out, int out_size, void* d_ws, size_t ws_size,
                              hipStream_t stream) {
    const float4* goal = (const float4*)d_in[0];   // [T, B, D] f32
    const float4* init = (const float4*)d_in[1];   // [1, B, D] f32
    float4* out  = (float4*)d_out;                 // outputs | final | final
    float4* sums = (float4*)d_ws;                  // (CHUNKS-1)*BD4 float4 = 1.75 MiB

    SumGoalHistory_chunksums<<<(CHUNKS - 1) * BD4 / 256, 256, 0, stream>>>(goal, sums);
    SumGoalHistory_scan<<<CHUNKS * BD4 / 256, 256, 0, stream>>>(goal, init, sums, out);
}

// Round 7
// 251.691 us; speedup vs baseline: 1.0101x; 1.0101x over previous
//
#include <hip/hip_runtime.h>

// Problem constants: T=512, B=64, D=1024, fp32.
#define T_DIM   512
#define BD      65536          // B*D floats per time slice
#define BD4     16384          // BD / 4 (float4 columns)
#define CHUNKS  16
#define CHUNK_T 32             // T_DIM / CHUNKS

// Native clang vector for nontemporal stores (HIP float4 is a class type,
// rejected by __builtin_nontemporal_store).
typedef float nfloat4 __attribute__((ext_vector_type(4)));

__device__ __forceinline__ float sigmoid_fast(float x) {
    // 1 / (1 + e^-x) via hw exp2 + hw rcp (~2 ULP, fine vs f32 reference)
    float e = __expf(-x);
    return __builtin_amdgcn_rcpf(1.0f + e);
}

// K1: per-column sum of each T-chunk (chunks 0..CHUNKS-2; last chunk's sum
// is never needed as an offset). Reads (C-1)/C of goal cold; primes L3 for K2.
__global__ __launch_bounds__(256)
void SumGoalHistory_chunksums(const float4* __restrict__ goal,
                              float4* __restrict__ sums) {
    int gid = blockIdx.x * 256 + threadIdx.x;     // [0, (CHUNKS-1)*BD4)
    int c = gid >> 14;                            // / BD4
    int i = gid & (BD4 - 1);
    const float4* p = goal + (size_t)c * CHUNK_T * BD4 + i;
    float sx = 0.f, sy = 0.f, sz = 0.f, sw = 0.f;
    #pragma unroll 8
    for (int t = 0; t < CHUNK_T; ++t) {
        float4 v = p[(size_t)t * BD4];
        sx += v.x; sy += v.y; sz += v.z; sw += v.w;
    }
    sums[c * BD4 + i] = make_float4(sx, sy, sz, sw);
}

// K2: each thread owns (chunk c, float4-column i). Offset = init + prefix of
// chunk sums, then 32-step sequential scan: acc += goal; out = sigmoid(acc).
// 1024 blocks = 16 waves/CU for latency hiding; goal re-read should hit L3
// (134 MB < 256 MB Infinity Cache, primed by K1).
__global__ __launch_bounds__(256)
void SumGoalHistory_scan(const float4* __restrict__ goal,
                         const float4* __restrict__ init,
                         const float4* __restrict__ sums,
                         float4* __restrict__ out) {
    int gid = blockIdx.x * 256 + threadIdx.x;     // [0, CHUNKS*BD4)
    int c = gid >> 14;                            // uniform per block (64 blocks/chunk)
    int i = gid & (BD4 - 1);

    float4 a = init[i];
    float ax = a.x, ay = a.y, az = a.z, aw = a.w;
    for (int cc = 0; cc < c; ++cc) {
        float4 s = sums[cc * BD4 + i];
        ax += s.x; ay += s.y; az += s.z; aw += s.w;
    }

    const float4* p = goal + (size_t)c * CHUNK_T * BD4 + i;
    nfloat4*      o = (nfloat4*)out + (size_t)c * CHUNK_T * BD4 + i;
    #pragma unroll 4
    for (int t = 0; t < CHUNK_T; ++t) {
        float4 v = p[(size_t)t * BD4];
        ax += v.x; ay += v.y; az += v.z; aw += v.w;
        nfloat4 r;
        r.x = sigmoid_fast(ax);
        r.y = sigmoid_fast(ay);
        r.z = sigmoid_fast(az);
        r.w = sigmoid_fast(aw);
        // nt store: outputs are never re-read; keep them out of L3 so goal stays hot
        __builtin_nontemporal_store(r, o + (size_t)t * BD4);
    }

    if (c == CHUNKS - 1) {
        // final_state written twice: d_out layout = outputs | final | final
        float4 f = make_float4(ax, ay, az, aw);
        float4* fin = out + (size_t)T_DIM * BD4;
        fin[i] = f;
        fin[BD4 + i] = f;
    }
}

extern "C" void kernel_launch(void* const* d_in, const int* in_sizes, int n_in,
                              void* d_out, int out_size, void* d_ws, size_t ws_size,
                              hipStream_t stream) {
    const float4* goal = (const float4*)d_in[0];   // [T, B, D] f32
    const float4* init = (const float4*)d_in[1];   // [1, B, D] f32
    float4* out  = (float4*)d_out;                 // outputs | final | final
    float4* sums = (float4*)d_ws;                  // (CHUNKS-1)*BD4 float4 = 3.75 MiB

    SumGoalHistory_chunksums<<<(CHUNKS - 1) * BD4 / 256, 256, 0, stream>>>(goal, sums);
    SumGoalHistory_scan<<<CHUNKS * BD4 / 256, 256, 0, stream>>>(goal, init, sums, out);
}